// Round 8
// baseline (344.557 us; speedup 1.0000x reference)
//
#include <hip/hip_runtime.h>

typedef __attribute__((ext_vector_type(8))) __bf16 bf16x8;
typedef __attribute__((ext_vector_type(4))) float f32x4;
typedef __attribute__((ext_vector_type(8))) unsigned short u16x8;
typedef __attribute__((ext_vector_type(4))) unsigned short u16x4;
typedef unsigned short u16;
typedef unsigned int u32;

#define NINP 1024
#define NOUT 1024
#define NSLOTS 15
#define BB 4096

__device__ __forceinline__ u16 f2bf(float x) {
  u32 u = __float_as_uint(x);
  u = (u + 0x7FFFu + ((u >> 16) & 1u)) >> 16;
  return (u16)u;
}
__device__ __forceinline__ float bf2f(u16 u) {
  return __uint_as_float(((u32)u) << 16);
}
__device__ __forceinline__ float sigf(float x) {
  return 1.0f / (1.0f + __expf(-x));
}
__device__ __forceinline__ float tanhfast(float x) {
  return 1.0f - 2.0f / (__expf(2.0f * x) + 1.0f);
}

__device__ __forceinline__ void llds16(const u16* g, const u16* l) {
  __builtin_amdgcn_global_load_lds(
      (const __attribute__((address_space(1))) void*)g,
      (__attribute__((address_space(3))) void*)l, 16, 0, 0);
}

// ---------------------------------------------------------------------------
// K0: f32 -> bf16 conversions. All reads are single-use -> nt loads.
//   X2[b][0:1024]    = input[b] ; X2[b][1024:2048] = memory_h[b][0]
//   WP[n][0:2048]    = W_proj[n]
//   WG[n][0:1024]    = W_ih[n] ; WG[n][1024:2048] = W_hh[n]
// ---------------------------------------------------------------------------
__global__ void convert_kernel(const float* __restrict__ input,
                               const float* __restrict__ mem_h,
                               const float* __restrict__ W_proj,
                               const float* __restrict__ W_ih,
                               const float* __restrict__ W_hh,
                               u16* __restrict__ X2, u16* __restrict__ WP,
                               u16* __restrict__ WG) {
  const int S0 = 4194304, S1 = 4194304, S2 = 2097152, S3 = 4194304, S4 = 4194304;
  const int total4 = (S0 + S1 + S2 + S3 + S4) >> 2;
  for (int i4 = blockIdx.x * blockDim.x + threadIdx.x; i4 < total4;
       i4 += gridDim.x * blockDim.x) {
    int i = i4 << 2;
    const float* src;
    u16* dst;
    if (i < S0) {
      int j = i, b = j >> 10, d = j & 1023;
      src = input + j;
      dst = X2 + ((size_t)b << 11) + d;
    } else if (i < S0 + S1) {
      int j = i - S0, b = j >> 10, d = j & 1023;
      src = mem_h + (size_t)b * (NSLOTS * NOUT) + d;
      dst = X2 + ((size_t)b << 11) + 1024 + d;
    } else if (i < S0 + S1 + S2) {
      int j = i - S0 - S1;
      src = W_proj + j;
      dst = WP + j;
    } else if (i < S0 + S1 + S2 + S3) {
      int j = i - S0 - S1 - S2, n = j >> 10, k = j & 1023;
      src = W_ih + j;
      dst = WG + ((size_t)n << 11) + k;
    } else {
      int j = i - S0 - S1 - S2 - S3, n = j >> 10, k = j & 1023;
      src = W_hh + j;
      dst = WG + ((size_t)n << 11) + 1024 + k;
    }
    f32x4 v = __builtin_nontemporal_load((const f32x4*)src);
    ushort4 o;
    o.x = f2bf(v[0]); o.y = f2bf(v[1]); o.z = f2bf(v[2]); o.w = f2bf(v[3]);
    *(ushort4*)dst = o;
  }
}

// ---------------------------------------------------------------------------
// 128x128 bf16 GEMM (m97-style) — GEMM1 (key), bf16 output.
// ---------------------------------------------------------------------------
__global__ __launch_bounds__(256) void gemm_bt(
    const u16* __restrict__ A, const u16* __restrict__ W,
    const float* __restrict__ bias1, u16* __restrict__ Cb, int M, int N,
    int K) {
  __shared__ u16 sA[2][128 * 32];
  __shared__ u16 sB[2][128 * 32];
  const int t = threadIdx.x;
  const int wave = t >> 6, lane = t & 63;
  const int m0 = blockIdx.y * 128, n0 = blockIdx.x * 128;
  const int wr = (wave >> 1) * 64, wc = (wave & 1) * 64;

  f32x4 acc[4][4] = {};

  const int row0 = t >> 2, col0 = (t & 3) * 8;
  const int row1 = (t + 256) >> 2;
  const u16* Ag0 = A + (size_t)(m0 + row0) * K + col0;
  const u16* Ag1 = A + (size_t)(m0 + row1) * K + col0;
  const u16* Wg0 = W + (size_t)(n0 + row0) * K + col0;
  const u16* Wg1 = W + (size_t)(n0 + row1) * K + col0;
  const int l0 = (wave * 64) * 8;
  const int l1 = (256 + wave * 64) * 8;

  auto stage = [&](int buf, int kt) {
    const int k0 = kt * 32;
    llds16(Ag0 + k0, &sA[buf][l0]);
    llds16(Ag1 + k0, &sA[buf][l1]);
    llds16(Wg0 + k0, &sB[buf][l0]);
    llds16(Wg1 + k0, &sB[buf][l1]);
  };

  const int lrow = lane & 15;
  const int kq = (lane >> 4) * 8;

  const int nk = K / 32;
  stage(0, 0);
  for (int kt = 0; kt < nk; ++kt) {
    __syncthreads();
    if (kt + 1 < nk) stage((kt + 1) & 1, kt + 1);
    const int buf = kt & 1;
    bf16x8 af[4], bfr[4];
#pragma unroll
    for (int mi = 0; mi < 4; ++mi)
      af[mi] = *(const bf16x8*)&sA[buf][(wr + mi * 16 + lrow) * 32 + kq];
#pragma unroll
    for (int ni = 0; ni < 4; ++ni)
      bfr[ni] = *(const bf16x8*)&sB[buf][(wc + ni * 16 + lrow) * 32 + kq];
#pragma unroll
    for (int mi = 0; mi < 4; ++mi)
#pragma unroll
      for (int ni = 0; ni < 4; ++ni)
        acc[mi][ni] = __builtin_amdgcn_mfma_f32_16x16x32_bf16(
            af[mi], bfr[ni], acc[mi][ni], 0, 0, 0);
  }

  const int crow = (lane >> 4) * 4;
  const int ccol = lane & 15;
#pragma unroll
  for (int mi = 0; mi < 4; ++mi) {
#pragma unroll
    for (int ni = 0; ni < 4; ++ni) {
      int row = m0 + wr + mi * 16 + crow;
      int col = n0 + wc + ni * 16 + ccol;
      float bv = bias1 ? bias1[col] : 0.0f;
#pragma unroll
      for (int r = 0; r < 4; ++r)
        Cb[(size_t)(row + r) * N + col] = f2bf(acc[mi][ni][r] + bv);
    }
  }
}

// ---------------------------------------------------------------------------
// 256x256 8-phase bf16 GEMM (round-4 verified schedule), bf16 gates output.
// UNCHANGED — do not touch the verified schedule.
// ---------------------------------------------------------------------------
__global__ __launch_bounds__(512, 2) void gemm256(
    const u16* __restrict__ A, const u16* __restrict__ W,
    const float* __restrict__ bias1, const float* __restrict__ bias2,
    u16* __restrict__ Cb, int M, int N, int K) {
  extern __shared__ __align__(16) u16 smem[];
  u16* sA = smem;           // 32768 u16
  u16* sB = smem + 32768;   // 32768 u16

  const int t = threadIdx.x;
  const int wid = t >> 6, lane = t & 63;
  const int nbx = N >> 8;
  const int nb = (M >> 8) * nbx;
  const int cpx = nb >> 3;
  const int bid = blockIdx.x;
  const int wg = (bid & 7) * cpx + (bid >> 3);  // bijective: nb%8==0
  const int m0 = (wg / nbx) << 8;
  const int n0 = (wg % nbx) << 8;

  const int wm = wid >> 2, wn = wid & 3;  // wave tile: 128 x 64

  f32x4 acc[8][4] = {};

  const int src_swz = ((lane >> 5) & 1) << 4;
  const u16* gA[4];
  const u16* gB[4];
#pragma unroll
  for (int j = 0; j < 4; ++j) {
    int row = (j & 1) * 128 + (t >> 2);
    int col = (j >> 1) * 32 + ((((t & 3) * 8) ^ src_swz));
    gA[j] = A + (size_t)(m0 + row) * K + col;
    gB[j] = W + (size_t)(n0 + row) * K + col;
  }
  auto stage = [&](int kt, int buf) {
    const int ko = kt * 64;
    const int lb = buf * 16384;
#pragma unroll
    for (int j = 0; j < 4; ++j)
      llds16(gA[j] + ko, sA + lb + (j * 512 + wid * 64) * 8);
#pragma unroll
    for (int j = 0; j < 4; ++j)
      llds16(gB[j] + ko, sB + lb + (j * 512 + wid * 64) * 8);
  };

  const int lrow = lane & 15;
  const int lcol = ((lane >> 4) * 8) ^ (((lane >> 3) & 1) << 4);
  const u16* pA = sA + (wm * 128 + lrow) * 32 + lcol;
  const u16* pB = sB + (wn * 64 + lrow) * 32 + lcol;

  const int NKT = K >> 6;
  stage(0, 0);
  for (int kt = 0; kt < NKT; ++kt) {
    const int buf = kt & 1;
    if (kt + 1 < NKT) {
      stage(kt + 1, buf ^ 1);
      asm volatile("s_waitcnt vmcnt(8)" ::: "memory");
      __builtin_amdgcn_sched_barrier(0);
    } else {
      asm volatile("s_waitcnt vmcnt(0)" ::: "memory");
      __builtin_amdgcn_sched_barrier(0);
    }
    __builtin_amdgcn_s_barrier();

    const u16* bA = pA + buf * 16384;
    const u16* bB = pB + buf * 16384;

    bf16x8 bf[4][2];
#pragma unroll
    for (int ni = 0; ni < 4; ++ni)
#pragma unroll
      for (int ks = 0; ks < 2; ++ks)
        bf[ni][ks] = *(const bf16x8*)(bB + ks * 8192 + ni * (16 * 32));

#pragma unroll
    for (int ph = 0; ph < 4; ++ph) {
      bf16x8 af[2][2];
#pragma unroll
      for (int m2 = 0; m2 < 2; ++m2)
#pragma unroll
        for (int ks = 0; ks < 2; ++ks)
          af[m2][ks] =
              *(const bf16x8*)(bA + ks * 8192 + (ph * 2 + m2) * (16 * 32));
      __builtin_amdgcn_s_setprio(1);
#pragma unroll
      for (int ks = 0; ks < 2; ++ks)
#pragma unroll
        for (int m2 = 0; m2 < 2; ++m2)
#pragma unroll
          for (int ni = 0; ni < 4; ++ni)
            acc[ph * 2 + m2][ni] = __builtin_amdgcn_mfma_f32_16x16x32_bf16(
                af[m2][ks], bf[ni][ks], acc[ph * 2 + m2][ni], 0, 0, 0);
      __builtin_amdgcn_s_setprio(0);
      __builtin_amdgcn_s_barrier();
    }
  }

  const int crow = (lane >> 4) * 4;
  const int ccol = lane & 15;
#pragma unroll
  for (int mi = 0; mi < 8; ++mi) {
#pragma unroll
    for (int ni = 0; ni < 4; ++ni) {
      int row = m0 + wm * 128 + mi * 16 + crow;
      int col = n0 + wn * 64 + ni * 16 + ccol;
      float bv = bias1[col] + bias2[col];
#pragma unroll
      for (int r = 0; r < 4; ++r)
        Cb[(size_t)(row + r) * N + col] = f2bf(acc[mi][ni][r] + bv);
    }
  }
}

// ---------------------------------------------------------------------------
// K2: attention + softmax + sel_h/sel_c + memory roll. key bf16, selc bf16.
// nt on all streaming traffic (mh/mc loads, roll stores, keyb/rmask loads).
// ---------------------------------------------------------------------------
__global__ __launch_bounds__(256) void attn_kernel(
    const float* __restrict__ mem_h, const float* __restrict__ mem_c,
    const u16* __restrict__ keyb, const float* __restrict__ gate_time,
    const float* __restrict__ rmask, float* __restrict__ out_mh,
    float* __restrict__ out_mc, float* __restrict__ out_att,
    u16* __restrict__ X2, u16* __restrict__ selcb) {
  const int b = blockIdx.x;
  const int t = threadIdx.x;
  const int lane = t & 63, wave = t >> 6;

  const f32x4* mh4 = (const f32x4*)(mem_h + (size_t)b * (NSLOTS * NOUT));
  const f32x4* mc4 = (const f32x4*)(mem_c + (size_t)b * (NSLOTS * NOUT));
  u16x4 kb = __builtin_nontemporal_load(
      (const u16x4*)(keyb + ((size_t)b << 10) + t * 4));
  f32x4 key4 = {bf2f(kb[0]), bf2f(kb[1]), bf2f(kb[2]), bf2f(kb[3])};

  f32x4 h[NSLOTS];
  float lg[NSLOTS];
#pragma unroll
  for (int s = 0; s < NSLOTS; ++s) {
    h[s] = __builtin_nontemporal_load(&mh4[s * 256 + t]);
    lg[s] = h[s][0] * key4[0] + h[s][1] * key4[1] + h[s][2] * key4[2] +
            h[s][3] * key4[3];
  }

  __shared__ float red[NSLOTS][4];
#pragma unroll
  for (int s = 0; s < NSLOTS; ++s) {
    float v = lg[s];
    v += __shfl_xor(v, 32); v += __shfl_xor(v, 16); v += __shfl_xor(v, 8);
    v += __shfl_xor(v, 4);  v += __shfl_xor(v, 2);  v += __shfl_xor(v, 1);
    if (lane == 0) red[s][wave] = v;
  }
  __syncthreads();

  float att[NSLOTS];
  float mx = -1e30f;
#pragma unroll
  for (int s = 0; s < NSLOTS; ++s) {
    float v = red[s][0] + red[s][1] + red[s][2] + red[s][3];
    att[s] = v * 0.03125f;
    mx = fmaxf(mx, att[s]);
  }
  float ssum = 0.0f;
#pragma unroll
  for (int s = 0; s < NSLOTS; ++s) {
    att[s] = __expf(att[s] - mx) * gate_time[b * NSLOTS + s];
    ssum += att[s];
  }
  float inv = 1.0f / ssum;
#pragma unroll
  for (int s = 0; s < NSLOTS; ++s) att[s] *= inv;
  if (t == 0) {
#pragma unroll
    for (int s = 0; s < NSLOTS; ++s) out_att[(size_t)b * NSLOTS + s] = att[s];
  }

  // sel_h + roll of memory_h (slot s -> s+1)
  f32x4 sh = {0, 0, 0, 0};
  f32x4* omh = (f32x4*)(out_mh + (size_t)b * (NSLOTS * NOUT));
#pragma unroll
  for (int s = 0; s < NSLOTS; ++s) {
    sh += att[s] * h[s];
    if (s < NSLOTS - 1)
      __builtin_nontemporal_store(h[s], &omh[(s + 1) * 256 + t]);
  }
  f32x4 rm = __builtin_nontemporal_load(
      (const f32x4*)(rmask + ((size_t)b << 10) + t * 4));
  sh *= rm;
  ushort4 shb;
  shb.x = f2bf(sh[0]); shb.y = f2bf(sh[1]);
  shb.z = f2bf(sh[2]); shb.w = f2bf(sh[3]);
  ((ushort4*)(X2 + ((size_t)b << 11) + 1024))[t] = shb;

  // sel_c + roll of memory_c (single streaming pass)
  f32x4 sc = {0, 0, 0, 0};
  f32x4* omc = (f32x4*)(out_mc + (size_t)b * (NSLOTS * NOUT));
#pragma unroll
  for (int s = 0; s < NSLOTS; ++s) {
    f32x4 c = __builtin_nontemporal_load(&mc4[s * 256 + t]);
    sc += att[s] * c;
    if (s < NSLOTS - 1)
      __builtin_nontemporal_store(c, &omc[(s + 1) * 256 + t]);
  }
  ushort4 scb;
  scb.x = f2bf(sc[0]); scb.y = f2bf(sc[1]);
  scb.z = f2bf(sc[2]); scb.w = f2bf(sc[3]);
  ((ushort4*)(selcb + ((size_t)b << 10)))[t] = scb;
}

// ---------------------------------------------------------------------------
// K4: LSTM elementwise, 16B/lane. nt loads (gates/selcb single-use) +
// nt stores.
// ---------------------------------------------------------------------------
__global__ __launch_bounds__(256) void lstm_ew(const u16* __restrict__ gates,
                                               const u16* __restrict__ selcb,
                                               float* __restrict__ out_h,
                                               float* __restrict__ out_mh,
                                               float* __restrict__ out_mc) {
  int gid = blockIdx.x * blockDim.x + threadIdx.x;  // 0 .. 4096*128
  int b = gid >> 7, d8 = (gid & 127) << 3;
  const u16* gbase = gates + ((size_t)b << 12) + d8;
  u16x8 iu = __builtin_nontemporal_load((const u16x8*)(gbase));
  u16x8 fu = __builtin_nontemporal_load((const u16x8*)(gbase + 1024));
  u16x8 gu = __builtin_nontemporal_load((const u16x8*)(gbase + 2048));
  u16x8 ou = __builtin_nontemporal_load((const u16x8*)(gbase + 3072));
  u16x8 su = __builtin_nontemporal_load(
      (const u16x8*)(selcb + ((size_t)b << 10) + d8));

  float hv[8], cvv[8];
#pragma unroll
  for (int j = 0; j < 8; ++j) {
    float ii = sigf(bf2f(iu[j])), ff = sigf(bf2f(fu[j]));
    float gg = tanhfast(bf2f(gu[j])), oo = sigf(bf2f(ou[j]));
    float sc = bf2f(su[j]);
    cvv[j] = ff * sc + ii * gg;
    hv[j] = oo * tanhfast(cvv[j]);
  }
  f32x4 h0 = {hv[0], hv[1], hv[2], hv[3]};
  f32x4 h1 = {hv[4], hv[5], hv[6], hv[7]};
  f32x4 c0 = {cvv[0], cvv[1], cvv[2], cvv[3]};
  f32x4 c1 = {cvv[4], cvv[5], cvv[6], cvv[7]};
  float* oh = out_h + ((size_t)b << 10) + d8;
  float* omh = out_mh + (size_t)b * (NSLOTS * NOUT) + d8;
  float* omc = out_mc + (size_t)b * (NSLOTS * NOUT) + d8;
  __builtin_nontemporal_store(h0, (f32x4*)oh);
  __builtin_nontemporal_store(h1, (f32x4*)(oh + 4));
  __builtin_nontemporal_store(h0, (f32x4*)omh);
  __builtin_nontemporal_store(h1, (f32x4*)(omh + 4));
  __builtin_nontemporal_store(c0, (f32x4*)omc);
  __builtin_nontemporal_store(c1, (f32x4*)(omc + 4));
}

// ---------------------------------------------------------------------------
extern "C" void kernel_launch(void* const* d_in, const int* in_sizes, int n_in,
                              void* d_out, int out_size, void* d_ws,
                              size_t ws_size, hipStream_t stream) {
  const float* input = (const float*)d_in[0];
  const float* gate_time = (const float*)d_in[1];
  const float* rmask = (const float*)d_in[2];
  const float* mem_h = (const float*)d_in[3];
  const float* mem_c = (const float*)d_in[4];
  const float* W_proj = (const float*)d_in[5];
  const float* b_proj = (const float*)d_in[6];
  const float* W_ih = (const float*)d_in[7];
  const float* W_hh = (const float*)d_in[8];
  const float* b_ih = (const float*)d_in[9];
  const float* b_hh = (const float*)d_in[10];

  float* out = (float*)d_out;
  float* out_h = out;
  float* out_mh = out + 4194304;
  float* out_mc = out_mh + 62914560;
  float* out_att = out_mc + 62914560;

  char* ws = (char*)d_ws;
  u16* X2 = (u16*)ws;                      // [4096,2048] bf16   16.78 MB
  u16* WP = (u16*)(ws + 16777216);         // [1024,2048] bf16    4.19 MB
  u16* WG = (u16*)(ws + 20971520);         // [4096,2048] bf16   16.78 MB
  u16* keyb = (u16*)(ws + 37748736);       // [4096,1024] bf16    8.39 MB
  u16* selcb = (u16*)(ws + 46137344);      // [4096,1024] bf16    8.39 MB
  u16* gates = (u16*)(ws + 54525952);      // [4096,4096] bf16   33.55 MB

  (void)hipFuncSetAttribute((const void*)gemm256,
                            hipFuncAttributeMaxDynamicSharedMemorySize, 131072);

  convert_kernel<<<2048, 256, 0, stream>>>(input, mem_h, W_proj, W_ih, W_hh, X2,
                                           WP, WG);
  // key = [x | h0] @ WP^T + b_proj   (M=4096, N=1024, K=2048), bf16 out
  gemm_bt<<<dim3(8, 32), 256, 0, stream>>>(X2, WP, b_proj, keyb, 4096, 1024,
                                           2048);
  attn_kernel<<<4096, 256, 0, stream>>>(mem_h, mem_c, keyb, gate_time, rmask,
                                        out_mh, out_mc, out_att, X2, selcb);
  // gates = [x | sel_h*rmask] @ [W_ih|W_hh]^T + b_ih + b_hh
  gemm256<<<256, 512, 131072, stream>>>(X2, WG, b_ih, b_hh, gates, 4096, 4096,
                                        2048);
  lstm_ew<<<2048, 256, 0, stream>>>(gates, selcb, out_h, out_mh, out_mc);
}

// Round 9
// 330.470 us; speedup vs baseline: 1.0426x; 1.0426x over previous
//
#include <hip/hip_runtime.h>

typedef __attribute__((ext_vector_type(8))) __bf16 bf16x8;
typedef __attribute__((ext_vector_type(4))) float f32x4;
typedef __attribute__((ext_vector_type(8))) unsigned short u16x8;
typedef __attribute__((ext_vector_type(4))) unsigned short u16x4;
typedef unsigned short u16;
typedef unsigned int u32;

#define NINP 1024
#define NOUT 1024
#define NSLOTS 15
#define BB 4096

__device__ __forceinline__ u16 f2bf(float x) {
  u32 u = __float_as_uint(x);
  u = (u + 0x7FFFu + ((u >> 16) & 1u)) >> 16;
  return (u16)u;
}
__device__ __forceinline__ float bf2f(u16 u) {
  return __uint_as_float(((u32)u) << 16);
}
__device__ __forceinline__ float sigf(float x) {
  return 1.0f / (1.0f + __expf(-x));
}
__device__ __forceinline__ float tanhfast(float x) {
  return 1.0f - 2.0f / (__expf(2.0f * x) + 1.0f);
}

__device__ __forceinline__ void llds16(const u16* g, const u16* l) {
  __builtin_amdgcn_global_load_lds(
      (const __attribute__((address_space(1))) void*)g,
      (__attribute__((address_space(3))) void*)l, 16, 0, 0);
}

// ---------------------------------------------------------------------------
// K0: f32 -> bf16 conversions. Plain loads (outputs are re-read by GEMMs;
// nt loads here regressed — round-8 A/B).
//   X2[b][0:1024]    = input[b] ; X2[b][1024:2048] = memory_h[b][0]
//   WP[n][0:2048]    = W_proj[n]
//   WG[n][0:1024]    = W_ih[n] ; WG[n][1024:2048] = W_hh[n]
// ---------------------------------------------------------------------------
__global__ void convert_kernel(const float* __restrict__ input,
                               const float* __restrict__ mem_h,
                               const float* __restrict__ W_proj,
                               const float* __restrict__ W_ih,
                               const float* __restrict__ W_hh,
                               u16* __restrict__ X2, u16* __restrict__ WP,
                               u16* __restrict__ WG) {
  const int S0 = 4194304, S1 = 4194304, S2 = 2097152, S3 = 4194304, S4 = 4194304;
  const int total4 = (S0 + S1 + S2 + S3 + S4) >> 2;
  for (int i4 = blockIdx.x * blockDim.x + threadIdx.x; i4 < total4;
       i4 += gridDim.x * blockDim.x) {
    int i = i4 << 2;
    const float* src;
    u16* dst;
    if (i < S0) {
      int j = i, b = j >> 10, d = j & 1023;
      src = input + j;
      dst = X2 + ((size_t)b << 11) + d;
    } else if (i < S0 + S1) {
      int j = i - S0, b = j >> 10, d = j & 1023;
      src = mem_h + (size_t)b * (NSLOTS * NOUT) + d;
      dst = X2 + ((size_t)b << 11) + 1024 + d;
    } else if (i < S0 + S1 + S2) {
      int j = i - S0 - S1;
      src = W_proj + j;
      dst = WP + j;
    } else if (i < S0 + S1 + S2 + S3) {
      int j = i - S0 - S1 - S2, n = j >> 10, k = j & 1023;
      src = W_ih + j;
      dst = WG + ((size_t)n << 11) + k;
    } else {
      int j = i - S0 - S1 - S2 - S3, n = j >> 10, k = j & 1023;
      src = W_hh + j;
      dst = WG + ((size_t)n << 11) + 1024 + k;
    }
    f32x4 v = *(const f32x4*)src;
    ushort4 o;
    o.x = f2bf(v[0]); o.y = f2bf(v[1]); o.z = f2bf(v[2]); o.w = f2bf(v[3]);
    *(ushort4*)dst = o;
  }
}

// ---------------------------------------------------------------------------
// 128x128 bf16 GEMM (m97-style) — GEMM1 (key), bf16 output.
// ---------------------------------------------------------------------------
__global__ __launch_bounds__(256) void gemm_bt(
    const u16* __restrict__ A, const u16* __restrict__ W,
    const float* __restrict__ bias1, u16* __restrict__ Cb, int M, int N,
    int K) {
  __shared__ u16 sA[2][128 * 32];
  __shared__ u16 sB[2][128 * 32];
  const int t = threadIdx.x;
  const int wave = t >> 6, lane = t & 63;
  const int m0 = blockIdx.y * 128, n0 = blockIdx.x * 128;
  const int wr = (wave >> 1) * 64, wc = (wave & 1) * 64;

  f32x4 acc[4][4] = {};

  const int row0 = t >> 2, col0 = (t & 3) * 8;
  const int row1 = (t + 256) >> 2;
  const u16* Ag0 = A + (size_t)(m0 + row0) * K + col0;
  const u16* Ag1 = A + (size_t)(m0 + row1) * K + col0;
  const u16* Wg0 = W + (size_t)(n0 + row0) * K + col0;
  const u16* Wg1 = W + (size_t)(n0 + row1) * K + col0;
  const int l0 = (wave * 64) * 8;
  const int l1 = (256 + wave * 64) * 8;

  auto stage = [&](int buf, int kt) {
    const int k0 = kt * 32;
    llds16(Ag0 + k0, &sA[buf][l0]);
    llds16(Ag1 + k0, &sA[buf][l1]);
    llds16(Wg0 + k0, &sB[buf][l0]);
    llds16(Wg1 + k0, &sB[buf][l1]);
  };

  const int lrow = lane & 15;
  const int kq = (lane >> 4) * 8;

  const int nk = K / 32;
  stage(0, 0);
  for (int kt = 0; kt < nk; ++kt) {
    __syncthreads();
    if (kt + 1 < nk) stage((kt + 1) & 1, kt + 1);
    const int buf = kt & 1;
    bf16x8 af[4], bfr[4];
#pragma unroll
    for (int mi = 0; mi < 4; ++mi)
      af[mi] = *(const bf16x8*)&sA[buf][(wr + mi * 16 + lrow) * 32 + kq];
#pragma unroll
    for (int ni = 0; ni < 4; ++ni)
      bfr[ni] = *(const bf16x8*)&sB[buf][(wc + ni * 16 + lrow) * 32 + kq];
#pragma unroll
    for (int mi = 0; mi < 4; ++mi)
#pragma unroll
      for (int ni = 0; ni < 4; ++ni)
        acc[mi][ni] = __builtin_amdgcn_mfma_f32_16x16x32_bf16(
            af[mi], bfr[ni], acc[mi][ni], 0, 0, 0);
  }

  const int crow = (lane >> 4) * 4;
  const int ccol = lane & 15;
#pragma unroll
  for (int mi = 0; mi < 4; ++mi) {
#pragma unroll
    for (int ni = 0; ni < 4; ++ni) {
      int row = m0 + wr + mi * 16 + crow;
      int col = n0 + wc + ni * 16 + ccol;
      float bv = bias1 ? bias1[col] : 0.0f;
#pragma unroll
      for (int r = 0; r < 4; ++r)
        Cb[(size_t)(row + r) * N + col] = f2bf(acc[mi][ni][r] + bv);
    }
  }
}

// ---------------------------------------------------------------------------
// 256x256 8-phase bf16 GEMM (round-4 verified schedule), bf16 gates output.
// UNCHANGED — do not touch the verified schedule.
// ---------------------------------------------------------------------------
__global__ __launch_bounds__(512, 2) void gemm256(
    const u16* __restrict__ A, const u16* __restrict__ W,
    const float* __restrict__ bias1, const float* __restrict__ bias2,
    u16* __restrict__ Cb, int M, int N, int K) {
  extern __shared__ __align__(16) u16 smem[];
  u16* sA = smem;           // 32768 u16
  u16* sB = smem + 32768;   // 32768 u16

  const int t = threadIdx.x;
  const int wid = t >> 6, lane = t & 63;
  const int nbx = N >> 8;
  const int nb = (M >> 8) * nbx;
  const int cpx = nb >> 3;
  const int bid = blockIdx.x;
  const int wg = (bid & 7) * cpx + (bid >> 3);  // bijective: nb%8==0
  const int m0 = (wg / nbx) << 8;
  const int n0 = (wg % nbx) << 8;

  const int wm = wid >> 2, wn = wid & 3;  // wave tile: 128 x 64

  f32x4 acc[8][4] = {};

  const int src_swz = ((lane >> 5) & 1) << 4;
  const u16* gA[4];
  const u16* gB[4];
#pragma unroll
  for (int j = 0; j < 4; ++j) {
    int row = (j & 1) * 128 + (t >> 2);
    int col = (j >> 1) * 32 + ((((t & 3) * 8) ^ src_swz));
    gA[j] = A + (size_t)(m0 + row) * K + col;
    gB[j] = W + (size_t)(n0 + row) * K + col;
  }
  auto stage = [&](int kt, int buf) {
    const int ko = kt * 64;
    const int lb = buf * 16384;
#pragma unroll
    for (int j = 0; j < 4; ++j)
      llds16(gA[j] + ko, sA + lb + (j * 512 + wid * 64) * 8);
#pragma unroll
    for (int j = 0; j < 4; ++j)
      llds16(gB[j] + ko, sB + lb + (j * 512 + wid * 64) * 8);
  };

  const int lrow = lane & 15;
  const int lcol = ((lane >> 4) * 8) ^ (((lane >> 3) & 1) << 4);
  const u16* pA = sA + (wm * 128 + lrow) * 32 + lcol;
  const u16* pB = sB + (wn * 64 + lrow) * 32 + lcol;

  const int NKT = K >> 6;
  stage(0, 0);
  for (int kt = 0; kt < NKT; ++kt) {
    const int buf = kt & 1;
    if (kt + 1 < NKT) {
      stage(kt + 1, buf ^ 1);
      asm volatile("s_waitcnt vmcnt(8)" ::: "memory");
      __builtin_amdgcn_sched_barrier(0);
    } else {
      asm volatile("s_waitcnt vmcnt(0)" ::: "memory");
      __builtin_amdgcn_sched_barrier(0);
    }
    __builtin_amdgcn_s_barrier();

    const u16* bA = pA + buf * 16384;
    const u16* bB = pB + buf * 16384;

    bf16x8 bf[4][2];
#pragma unroll
    for (int ni = 0; ni < 4; ++ni)
#pragma unroll
      for (int ks = 0; ks < 2; ++ks)
        bf[ni][ks] = *(const bf16x8*)(bB + ks * 8192 + ni * (16 * 32));

#pragma unroll
    for (int ph = 0; ph < 4; ++ph) {
      bf16x8 af[2][2];
#pragma unroll
      for (int m2 = 0; m2 < 2; ++m2)
#pragma unroll
        for (int ks = 0; ks < 2; ++ks)
          af[m2][ks] =
              *(const bf16x8*)(bA + ks * 8192 + (ph * 2 + m2) * (16 * 32));
      __builtin_amdgcn_s_setprio(1);
#pragma unroll
      for (int ks = 0; ks < 2; ++ks)
#pragma unroll
        for (int m2 = 0; m2 < 2; ++m2)
#pragma unroll
          for (int ni = 0; ni < 4; ++ni)
            acc[ph * 2 + m2][ni] = __builtin_amdgcn_mfma_f32_16x16x32_bf16(
                af[m2][ks], bf[ni][ks], acc[ph * 2 + m2][ni], 0, 0, 0);
      __builtin_amdgcn_s_setprio(0);
      __builtin_amdgcn_s_barrier();
    }
  }

  const int crow = (lane >> 4) * 4;
  const int ccol = lane & 15;
#pragma unroll
  for (int mi = 0; mi < 8; ++mi) {
#pragma unroll
    for (int ni = 0; ni < 4; ++ni) {
      int row = m0 + wm * 128 + mi * 16 + crow;
      int col = n0 + wn * 64 + ni * 16 + ccol;
      float bv = bias1[col] + bias2[col];
#pragma unroll
      for (int r = 0; r < 4; ++r)
        Cb[(size_t)(row + r) * N + col] = f2bf(acc[mi][ni][r] + bv);
    }
  }
}

// ---------------------------------------------------------------------------
// K2: attention + softmax + sel_h/sel_c + memory roll. key bf16, selc bf16.
// nt STORES on the rolled slots (dead streams); plain loads (round-8 A/B:
// nt loads regressed).
// ---------------------------------------------------------------------------
__global__ __launch_bounds__(256) void attn_kernel(
    const float* __restrict__ mem_h, const float* __restrict__ mem_c,
    const u16* __restrict__ keyb, const float* __restrict__ gate_time,
    const float* __restrict__ rmask, float* __restrict__ out_mh,
    float* __restrict__ out_mc, float* __restrict__ out_att,
    u16* __restrict__ X2, u16* __restrict__ selcb) {
  const int b = blockIdx.x;
  const int t = threadIdx.x;
  const int lane = t & 63, wave = t >> 6;

  const f32x4* mh4 = (const f32x4*)(mem_h + (size_t)b * (NSLOTS * NOUT));
  const f32x4* mc4 = (const f32x4*)(mem_c + (size_t)b * (NSLOTS * NOUT));
  ushort4 kb = ((const ushort4*)(keyb + ((size_t)b << 10)))[t];
  f32x4 key4 = {bf2f(kb.x), bf2f(kb.y), bf2f(kb.z), bf2f(kb.w)};

  f32x4 h[NSLOTS];
  float lg[NSLOTS];
#pragma unroll
  for (int s = 0; s < NSLOTS; ++s) {
    h[s] = __builtin_nontemporal_load(&mh4[s * 256 + t]);
    lg[s] = h[s][0] * key4[0] + h[s][1] * key4[1] + h[s][2] * key4[2] +
            h[s][3] * key4[3];
  }

  __shared__ float red[NSLOTS][4];
#pragma unroll
  for (int s = 0; s < NSLOTS; ++s) {
    float v = lg[s];
    v += __shfl_xor(v, 32); v += __shfl_xor(v, 16); v += __shfl_xor(v, 8);
    v += __shfl_xor(v, 4);  v += __shfl_xor(v, 2);  v += __shfl_xor(v, 1);
    if (lane == 0) red[s][wave] = v;
  }
  __syncthreads();

  float att[NSLOTS];
  float mx = -1e30f;
#pragma unroll
  for (int s = 0; s < NSLOTS; ++s) {
    float v = red[s][0] + red[s][1] + red[s][2] + red[s][3];
    att[s] = v * 0.03125f;
    mx = fmaxf(mx, att[s]);
  }
  float ssum = 0.0f;
#pragma unroll
  for (int s = 0; s < NSLOTS; ++s) {
    att[s] = __expf(att[s] - mx) * gate_time[b * NSLOTS + s];
    ssum += att[s];
  }
  float inv = 1.0f / ssum;
#pragma unroll
  for (int s = 0; s < NSLOTS; ++s) att[s] *= inv;
  if (t == 0) {
#pragma unroll
    for (int s = 0; s < NSLOTS; ++s) out_att[(size_t)b * NSLOTS + s] = att[s];
  }

  // sel_h + roll of memory_h (slot s -> s+1)
  f32x4 sh = {0, 0, 0, 0};
  f32x4* omh = (f32x4*)(out_mh + (size_t)b * (NSLOTS * NOUT));
#pragma unroll
  for (int s = 0; s < NSLOTS; ++s) {
    sh += att[s] * h[s];
    if (s < NSLOTS - 1)
      __builtin_nontemporal_store(h[s], &omh[(s + 1) * 256 + t]);
  }
  f32x4 rm = *(const f32x4*)(rmask + ((size_t)b << 10) + t * 4);
  sh *= rm;
  ushort4 shb;
  shb.x = f2bf(sh[0]); shb.y = f2bf(sh[1]);
  shb.z = f2bf(sh[2]); shb.w = f2bf(sh[3]);
  ((ushort4*)(X2 + ((size_t)b << 11) + 1024))[t] = shb;

  // sel_c + roll of memory_c (single streaming pass)
  f32x4 sc = {0, 0, 0, 0};
  f32x4* omc = (f32x4*)(out_mc + (size_t)b * (NSLOTS * NOUT));
#pragma unroll
  for (int s = 0; s < NSLOTS; ++s) {
    f32x4 c = __builtin_nontemporal_load(&mc4[s * 256 + t]);
    sc += att[s] * c;
    if (s < NSLOTS - 1)
      __builtin_nontemporal_store(c, &omc[(s + 1) * 256 + t]);
  }
  ushort4 scb;
  scb.x = f2bf(sc[0]); scb.y = f2bf(sc[1]);
  scb.z = f2bf(sc[2]); scb.w = f2bf(sc[3]);
  ((ushort4*)(selcb + ((size_t)b << 10)))[t] = scb;
}

// ---------------------------------------------------------------------------
// K4: LSTM elementwise, 16B/lane. Plain loads (gates/selcb are L2-resident
// from their producers — round-8 A/B showed nt loads regress); nt stores.
// ---------------------------------------------------------------------------
__global__ __launch_bounds__(256) void lstm_ew(const u16* __restrict__ gates,
                                               const u16* __restrict__ selcb,
                                               float* __restrict__ out_h,
                                               float* __restrict__ out_mh,
                                               float* __restrict__ out_mc) {
  int gid = blockIdx.x * blockDim.x + threadIdx.x;  // 0 .. 4096*128
  int b = gid >> 7, d8 = (gid & 127) << 3;
  const u16* gbase = gates + ((size_t)b << 12) + d8;
  u16x8 iu = *(const u16x8*)(gbase);
  u16x8 fu = *(const u16x8*)(gbase + 1024);
  u16x8 gu = *(const u16x8*)(gbase + 2048);
  u16x8 ou = *(const u16x8*)(gbase + 3072);
  u16x8 su = *(const u16x8*)(selcb + ((size_t)b << 10) + d8);

  float hv[8], cvv[8];
#pragma unroll
  for (int j = 0; j < 8; ++j) {
    float ii = sigf(bf2f(iu[j])), ff = sigf(bf2f(fu[j]));
    float gg = tanhfast(bf2f(gu[j])), oo = sigf(bf2f(ou[j]));
    float sc = bf2f(su[j]);
    cvv[j] = ff * sc + ii * gg;
    hv[j] = oo * tanhfast(cvv[j]);
  }
  f32x4 h0 = {hv[0], hv[1], hv[2], hv[3]};
  f32x4 h1 = {hv[4], hv[5], hv[6], hv[7]};
  f32x4 c0 = {cvv[0], cvv[1], cvv[2], cvv[3]};
  f32x4 c1 = {cvv[4], cvv[5], cvv[6], cvv[7]};
  float* oh = out_h + ((size_t)b << 10) + d8;
  float* omh = out_mh + (size_t)b * (NSLOTS * NOUT) + d8;
  float* omc = out_mc + (size_t)b * (NSLOTS * NOUT) + d8;
  __builtin_nontemporal_store(h0, (f32x4*)oh);
  __builtin_nontemporal_store(h1, (f32x4*)(oh + 4));
  __builtin_nontemporal_store(h0, (f32x4*)omh);
  __builtin_nontemporal_store(h1, (f32x4*)(omh + 4));
  __builtin_nontemporal_store(c0, (f32x4*)omc);
  __builtin_nontemporal_store(c1, (f32x4*)(omc + 4));
}

// ---------------------------------------------------------------------------
extern "C" void kernel_launch(void* const* d_in, const int* in_sizes, int n_in,
                              void* d_out, int out_size, void* d_ws,
                              size_t ws_size, hipStream_t stream) {
  const float* input = (const float*)d_in[0];
  const float* gate_time = (const float*)d_in[1];
  const float* rmask = (const float*)d_in[2];
  const float* mem_h = (const float*)d_in[3];
  const float* mem_c = (const float*)d_in[4];
  const float* W_proj = (const float*)d_in[5];
  const float* b_proj = (const float*)d_in[6];
  const float* W_ih = (const float*)d_in[7];
  const float* W_hh = (const float*)d_in[8];
  const float* b_ih = (const float*)d_in[9];
  const float* b_hh = (const float*)d_in[10];

  float* out = (float*)d_out;
  float* out_h = out;
  float* out_mh = out + 4194304;
  float* out_mc = out_mh + 62914560;
  float* out_att = out_mc + 62914560;

  char* ws = (char*)d_ws;
  u16* X2 = (u16*)ws;                      // [4096,2048] bf16   16.78 MB
  u16* WP = (u16*)(ws + 16777216);         // [1024,2048] bf16    4.19 MB
  u16* WG = (u16*)(ws + 20971520);         // [4096,2048] bf16   16.78 MB
  u16* keyb = (u16*)(ws + 37748736);       // [4096,1024] bf16    8.39 MB
  u16* selcb = (u16*)(ws + 46137344);      // [4096,1024] bf16    8.39 MB
  u16* gates = (u16*)(ws + 54525952);      // [4096,4096] bf16   33.55 MB

  (void)hipFuncSetAttribute((const void*)gemm256,
                            hipFuncAttributeMaxDynamicSharedMemorySize, 131072);

  convert_kernel<<<2048, 256, 0, stream>>>(input, mem_h, W_proj, W_ih, W_hh, X2,
                                           WP, WG);
  // key = [x | h0] @ WP^T + b_proj   (M=4096, N=1024, K=2048), bf16 out
  gemm_bt<<<dim3(8, 32), 256, 0, stream>>>(X2, WP, b_proj, keyb, 4096, 1024,
                                           2048);
  attn_kernel<<<4096, 256, 0, stream>>>(mem_h, mem_c, keyb, gate_time, rmask,
                                        out_mh, out_mc, out_att, X2, selcb);
  // gates = [x | sel_h*rmask] @ [W_ih|W_hh]^T + b_ih + b_hh
  gemm256<<<256, 512, 131072, stream>>>(X2, WG, b_ih, b_hh, gates, 4096, 4096,
                                        2048);
  lstm_ew<<<2048, 256, 0, stream>>>(gates, selcb, out_h, out_mh, out_mc);
}